// Round 4
// baseline (213.825 us; speedup 1.0000x reference)
//
#include <hip/hip_runtime.h>
#include <hip/hip_bf16.h>

typedef __attribute__((ext_vector_type(8))) short bf16x8;
typedef __attribute__((ext_vector_type(4))) float f32x4;

#define C1 0.180336880111112f   // 0.125 * log2(e) : folds the 1/sqrt(64) scale into exp2

static __device__ __forceinline__ unsigned short f2bf(float f) {
    union { float f; unsigned int i; } u; u.f = f;
    unsigned int r = u.i + 0x7fffu + ((u.i >> 16) & 1u);
    return (unsigned short)(r >> 16);
}
// pack two f32 -> two bf16 in one instr (no builtin on gfx950; RTNE)
static __device__ __forceinline__ unsigned int cvt_pk_bf16(float lo, float hi) {
    unsigned int r;
    asm("v_cvt_pk_bf16_f32 %0, %1, %2" : "=v"(r) : "v"(lo), "v"(hi));
    return r;
}

// ---------------- fused prep: cast x, transpose+cast both weights (one dispatch) ----------------
__global__ __launch_bounds__(256)
void prep_kernel(const float* __restrict__ x, const float* __restrict__ wA, const float* __restrict__ wP,
                 unsigned short* __restrict__ xb, unsigned short* __restrict__ wtA,
                 unsigned short* __restrict__ wtP) {
    const int bid = blockIdx.x, tid = threadIdx.x;
    if (bid < 2048) {
        int i0 = bid * 256 + tid;
        #pragma unroll
        for (int it = 0; it < 4; ++it) {
            int i = i0 + it * 524288;
            float4 v = reinterpret_cast<const float4*>(x)[i];
            ushort4 o;
            o.x = f2bf(v.x); o.y = f2bf(v.y); o.z = f2bf(v.z); o.w = f2bf(v.w);
            reinterpret_cast<ushort4*>(xb)[i] = o;
        }
    } else {
        const float* in; unsigned short* out; int R, C, bx, by;
        if (bid < 5120) { int l = bid - 2048; in = wA; out = wtA; R = 1024; C = 3072; bx = l % 96; by = l / 96; }
        else            { int l = bid - 5120; in = wP; out = wtP; R = 1024; C = 1024; bx = l % 32; by = l / 32; }
        __shared__ float tile[32][33];
        const int c0 = bx * 32, r0 = by * 32;
        const int tx = tid & 31, ty = tid >> 5;   // 32 x 8
        #pragma unroll
        for (int i = 0; i < 32; i += 8)
            tile[ty + i][tx] = in[(size_t)(r0 + ty + i) * C + c0 + tx];
        __syncthreads();
        #pragma unroll
        for (int i = 0; i < 32; i += 8)
            out[(size_t)(c0 + ty + i) * R + r0 + tx] = f2bf(tile[tx][ty + i]);
    }
}

// ---------------- GEMM: 128x128 tile, 4 waves, 32KB LDS (4 blocks/CU), T2 swizzle ----------------
// C[m][n] = sum_k A[m][k]*B[n][k], both bf16 K-contiguous.
// MODE 0: fp32 C [M][N].  MODE 1: scatter bf16 Q,K [bh][T][hd], V transposed [bh][hd][T].
template<int MODE>
__global__ __launch_bounds__(256, 4)
void gemm_bt2(const unsigned short* __restrict__ A,
              const unsigned short* __restrict__ B,
              void* __restrict__ Cout,
              int M, int N, int K) {
    __shared__ unsigned short As[8192];   // 128 rows x 64 k, 128B rows, swizzled content
    __shared__ unsigned short Bs[8192];
    const int tid = threadIdx.x;
    const int wave = tid >> 6, lane = tid & 63;
    const int wr = wave >> 1, wc = wave & 1;        // 2x2 waves, each 64x64 out
    const int lg = lane >> 4, lr = lane & 15;
    const int m0 = blockIdx.y * 128, n0 = blockIdx.x * 128;

    // staging: 256 thr x 16B = 4KB (32 rows) per issue, 4 issues each; inverse-swizzled source
    const int slot = tid * 16;
    const int srow = slot >> 7;                                // 0..31
    const int scol = ((slot & 127) ^ ((srow & 7) << 4)) >> 1;
    const int swz = (lr & 7) << 4;

    f32x4 acc[4][4] = {};

    for (int kt = 0; kt < K; kt += 64) {
        #pragma unroll
        for (int i = 0; i < 4; ++i) {
            __builtin_amdgcn_global_load_lds(
                (const __attribute__((address_space(1))) void*)(A + (size_t)(m0 + i * 32 + srow) * K + kt + scol),
                (__attribute__((address_space(3))) void*)(As + ((i * 4096 + slot) >> 1)), 16, 0, 0);
            __builtin_amdgcn_global_load_lds(
                (const __attribute__((address_space(1))) void*)(B + (size_t)(n0 + i * 32 + srow) * K + kt + scol),
                (__attribute__((address_space(3))) void*)(Bs + ((i * 4096 + slot) >> 1)), 16, 0, 0);
        }
        __syncthreads();
        #pragma unroll
        for (int kk = 0; kk < 2; ++kk) {
            bf16x8 af[4], bfr[4];
            #pragma unroll
            for (int mi = 0; mi < 4; ++mi)
                af[mi] = *reinterpret_cast<const bf16x8*>(
                    (const char*)As + (wr * 64 + mi * 16 + lr) * 128 + ((kk * 64 + lg * 16) ^ swz));
            #pragma unroll
            for (int ni = 0; ni < 4; ++ni)
                bfr[ni] = *reinterpret_cast<const bf16x8*>(
                    (const char*)Bs + (wc * 64 + ni * 16 + lr) * 128 + ((kk * 64 + lg * 16) ^ swz));
            #pragma unroll
            for (int mi = 0; mi < 4; ++mi)
                #pragma unroll
                for (int ni = 0; ni < 4; ++ni)
                    acc[mi][ni] = __builtin_amdgcn_mfma_f32_16x16x32_bf16(af[mi], bfr[ni], acc[mi][ni], 0, 0, 0);
        }
        __syncthreads();
    }

    if (MODE == 0) {
        float* C = (float*)Cout;
        #pragma unroll
        for (int mi = 0; mi < 4; ++mi)
            #pragma unroll
            for (int ni = 0; ni < 4; ++ni)
                #pragma unroll
                for (int r = 0; r < 4; ++r) {
                    int row = m0 + wr * 64 + mi * 16 + lg * 4 + r;
                    int col = n0 + wc * 64 + ni * 16 + lr;
                    C[(size_t)row * N + col] = acc[mi][ni][r];
                }
    } else {
        unsigned short* QKV = (unsigned short*)Cout;
        #pragma unroll
        for (int mi = 0; mi < 4; ++mi) {
            int rowb = m0 + wr * 64 + mi * 16 + lg * 4;   // 4 consecutive t
            int bb = rowb >> 11, t = rowb & 2047;
            #pragma unroll
            for (int ni = 0; ni < 4; ++ni) {
                int col = n0 + wc * 64 + ni * 16 + lr;
                int which = col >> 10;            // 0:q 1:k 2:v
                int hh = (col & 1023) >> 6;
                int d = col & 63;
                int bhh = bb * 16 + hh;
                if (which == 2) {
                    // V transposed: [bh][d][T], 4 consecutive t -> one 8B store
                    ushort4 o;
                    o.x = f2bf(acc[mi][ni][0]); o.y = f2bf(acc[mi][ni][1]);
                    o.z = f2bf(acc[mi][ni][2]); o.w = f2bf(acc[mi][ni][3]);
                    *reinterpret_cast<ushort4*>(QKV + (size_t)2 * 8388608 +
                                                ((size_t)bhh * 64 + d) * 2048 + t) = o;
                } else {
                    #pragma unroll
                    for (int r = 0; r < 4; ++r)
                        QKV[(size_t)which * 8388608 +
                            ((size_t)bhh * 2048 + t + r) * 64 + d] = f2bf(acc[mi][ni][r]);
                }
            }
        }
    }
}

// ---------------- flash attention (swapped-operand S^T formulation) ----------------
// Q,K: [bh][T][hd] bf16.  Vt: [bh][hd][T] bf16.  Y out: [B][T][H][hd] bf16.
// NO K/V LDS staging: per-head K+V (512KB) is L2-resident (16 q-blocks of a head
// land on one XCD: linear id = bh + 64*qt -> XCD = bh%8; 8 heads x 512KB = 4MB L2).
// K/V fragments load direct from global (same pattern as the validated qf load).
// -> no __syncthreads / vmcnt drains in the main loop; waves free-run over only
// their ACTIVE tiles. LDS = Ps only (18,432 B, verbatim validated layout).
__global__ __launch_bounds__(256)
void attn_fwd(const unsigned short* __restrict__ Qb,
              const unsigned short* __restrict__ Kb,
              const unsigned short* __restrict__ Vtb,
              unsigned short* __restrict__ Yb) {
    const int bh = blockIdx.x;
    const int qt = 15 - (int)blockIdx.y;         // biggest blocks dispatch first
    const int tid = threadIdx.x;
    const int wave = tid >> 6, lane = tid & 63;
    const int lg = lane >> 4, lr = lane & 15;
    const int b = bh >> 4, h = bh & 15;

    __shared__ unsigned short Ps[4][32][72];     // per-wave P [q][k], 144B row (16B aligned)

    const unsigned short* Qh = Qb + (size_t)bh * (2048 * 64);
    const unsigned short* Kh = Kb + (size_t)bh * (2048 * 64);
    const unsigned short* Vh = Vtb + (size_t)bh * (64 * 2048);

    const short one_bf = (short)0x3F80;
    const bf16x8 onesv = {one_bf, one_bf, one_bf, one_bf, one_bf, one_bf, one_bf, one_bf};

    const int q0 = qt * 128;
    const int wq0 = q0 + wave * 32;

    // hoist Q fragments (B-operand; wave owns 32 q-rows; col=lr -> q, k-slice = lg*8)
    bf16x8 qf[2][2];
    #pragma unroll
    for (int mi = 0; mi < 2; ++mi)
        #pragma unroll
        for (int kk = 0; kk < 2; ++kk)
            qf[mi][kk] = *reinterpret_cast<const bf16x8*>(
                Qh + (size_t)(wq0 + mi * 16 + lr) * 64 + kk * 32 + lg * 8);

    f32x4 oacc[4][2] = {};        // O^T[d-block nd][q-block mi]
    f32x4 sumacc[2] = {};         // row-sums (all 4 regs equal), col=q=lr
    float mst[2] = {-1e30f, -1e30f};

    // this wave's active kv tiles: kv0 < wq0 + 32
    const int ntw = (wq0 + 32 + 63) >> 6;

    #pragma unroll 1
    for (int t = 0; t < ntw; ++t) {
        const int kv0 = t << 6;

        // ---- S^T = K Q^T : kf direct from global (L2-hit), sacc[mi][ni]
        //      lane holds S^T[k=kv0+16ni+4lg+r][q=wq0+16mi+lr]
        f32x4 sacc[2][4] = {};
        __builtin_amdgcn_s_setprio(1);
        #pragma unroll
        for (int kk = 0; kk < 2; ++kk) {
            bf16x8 kf[4];
            #pragma unroll
            for (int ni = 0; ni < 4; ++ni)
                kf[ni] = *reinterpret_cast<const bf16x8*>(
                    Kh + (size_t)(kv0 + ni * 16 + lr) * 64 + kk * 32 + lg * 8);
            #pragma unroll
            for (int mi = 0; mi < 2; ++mi)
                #pragma unroll
                for (int ni = 0; ni < 4; ++ni)
                    sacc[mi][ni] = __builtin_amdgcn_mfma_f32_16x16x32_bf16(kf[ni], qf[mi][kk], sacc[mi][ni], 0, 0, 0);
        }
        __builtin_amdgcn_s_setprio(0);

        // ---- causal mask: only the diagonal tile of this wave ----
        if (kv0 + 64 > wq0) {
            #pragma unroll
            for (int mi = 0; mi < 2; ++mi)
                #pragma unroll
                for (int ni = 0; ni < 4; ++ni)
                    #pragma unroll
                    for (int r = 0; r < 4; ++r) {
                        int k = kv0 + ni * 16 + lg * 4 + r;
                        int q = wq0 + mi * 16 + lr;
                        if (k > q) sacc[mi][ni][r] = -1e30f;
                    }
        }

        // ---- online softmax: 16 k-values in-lane + 2 shfls across lg ----
        #pragma unroll
        for (int mi = 0; mi < 2; ++mi) {
            float m0v = fmaxf(fmaxf(sacc[mi][0][0], sacc[mi][0][1]), fmaxf(sacc[mi][0][2], sacc[mi][0][3]));
            float m1v = fmaxf(fmaxf(sacc[mi][1][0], sacc[mi][1][1]), fmaxf(sacc[mi][1][2], sacc[mi][1][3]));
            float m2v = fmaxf(fmaxf(sacc[mi][2][0], sacc[mi][2][1]), fmaxf(sacc[mi][2][2], sacc[mi][2][3]));
            float m3v = fmaxf(fmaxf(sacc[mi][3][0], sacc[mi][3][1]), fmaxf(sacc[mi][3][2], sacc[mi][3][3]));
            float mx = fmaxf(fmaxf(m0v, m1v), fmaxf(m2v, m3v));
            mx = fmaxf(mx, __shfl_xor(mx, 16));
            mx = fmaxf(mx, __shfl_xor(mx, 32));

            // defer-max (T13): skip rescale while growth bounded (P <= 2^11.5)
            if (!__all(mx <= mst[mi] + 64.0f)) {
                float mnew = fmaxf(mst[mi], mx);
                float alpha = __builtin_amdgcn_exp2f((mst[mi] - mnew) * C1);
                mst[mi] = mnew;
                sumacc[mi] *= alpha;
                #pragma unroll
                for (int nd = 0; nd < 4; ++nd)
                    oacc[nd][mi] *= alpha;
            }
            float mc = mst[mi] * C1;
            #pragma unroll
            for (int ni = 0; ni < 4; ++ni)
                #pragma unroll
                for (int r = 0; r < 4; ++r)
                    sacc[mi][ni][r] = __builtin_amdgcn_exp2f(__builtin_fmaf(sacc[mi][ni][r], C1, -mc));

            // ---- P^T -> Ps[q][k]: 4 consecutive k per (mi,ni) -> packed 8B writes
            #pragma unroll
            for (int ni = 0; ni < 4; ++ni) {
                uint2 w;
                w.x = cvt_pk_bf16(sacc[mi][ni][0], sacc[mi][ni][1]);
                w.y = cvt_pk_bf16(sacc[mi][ni][2], sacc[mi][ni][3]);
                *reinterpret_cast<uint2*>(&Ps[wave][mi * 16 + lr][ni * 16 + lg * 4]) = w;
            }
        }

        // ---- O^T += V^T P^T ; rowsum via ones-A MFMA ; vf direct from global (L2-hit)
        __builtin_amdgcn_s_setprio(1);
        #pragma unroll
        for (int ks = 0; ks < 2; ++ks) {
            bf16x8 pf[2], vf[4];
            #pragma unroll
            for (int mi = 0; mi < 2; ++mi)
                pf[mi] = *reinterpret_cast<const bf16x8*>(&Ps[wave][mi * 16 + lr][ks * 32 + lg * 8]);
            #pragma unroll
            for (int nd = 0; nd < 4; ++nd)
                vf[nd] = *reinterpret_cast<const bf16x8*>(
                    Vh + (size_t)(nd * 16 + lr) * 2048 + kv0 + ks * 32 + lg * 8);
            #pragma unroll
            for (int mi = 0; mi < 2; ++mi) {
                sumacc[mi] = __builtin_amdgcn_mfma_f32_16x16x32_bf16(onesv, pf[mi], sumacc[mi], 0, 0, 0);
                #pragma unroll
                for (int nd = 0; nd < 4; ++nd)
                    oacc[nd][mi] = __builtin_amdgcn_mfma_f32_16x16x32_bf16(vf[nd], pf[mi], oacc[nd][mi], 0, 0, 0);
            }
        }
        __builtin_amdgcn_s_setprio(0);
    }

    // ---- epilogue: y = O / l, packed 8B stores; lane holds d=16nd+4lg+r, q=16mi+lr ----
    #pragma unroll
    for (int mi = 0; mi < 2; ++mi) {
        float rinv = __builtin_amdgcn_rcpf(sumacc[mi][0]);
        int tq = wq0 + mi * 16 + lr;
        size_t base = (((size_t)(b * 2048 + tq)) * 16 + h) * 64 + lg * 4;
        #pragma unroll
        for (int nd = 0; nd < 4; ++nd) {
            uint2 w;
            w.x = cvt_pk_bf16(oacc[nd][mi][0] * rinv, oacc[nd][mi][1] * rinv);
            w.y = cvt_pk_bf16(oacc[nd][mi][2] * rinv, oacc[nd][mi][3] * rinv);
            *reinterpret_cast<uint2*>(Yb + base + nd * 16) = w;
        }
    }
}

// ---------------- launch ----------------
extern "C" void kernel_launch(void* const* d_in, const int* in_sizes, int n_in,
                              void* d_out, int out_size, void* d_ws, size_t ws_size,
                              hipStream_t stream) {
    const float* x      = (const float*)d_in[0];
    const float* w_attn = (const float*)d_in[1];
    const float* w_proj = (const float*)d_in[2];
    float* out = (float*)d_out;

    unsigned short* xb  = (unsigned short*)d_ws;          // 8192*1024
    unsigned short* wtA = xb  + 8388608;                  // 3072*1024
    unsigned short* wtP = wtA + 3145728;                  // 1024*1024
    unsigned short* qkv = wtP + 1048576;                  // q,k: [64][2048][64]; v: [64][64][2048]
    unsigned short* yb  = qkv + 3 * 8388608;              // 8192*1024

    prep_kernel<<<6144, 256, 0, stream>>>(x, w_attn, w_proj, xb, wtA, wtP);

    // qkv: M=8192, N=3072 -> grid (24, 64) = 1536 blocks, 4 blocks/CU (conflict-free 128^2)
    gemm_bt2<1><<<dim3(3072 / 128, 8192 / 128), 256, 0, stream>>>(xb, wtA, qkv, 8192, 3072, 1024);

    attn_fwd<<<dim3(64, 16), 256, 0, stream>>>(qkv, qkv + 8388608, qkv + 2 * 8388608, yb);

    // proj: M=8192, N=1024 -> grid (8, 64) = 512 blocks, 4 blocks/CU
    gemm_bt2<0><<<dim3(1024 / 128, 8192 / 128), 256, 0, stream>>>(yb, wtP, out, 8192, 1024, 1024);
}

// Round 5
// 163.598 us; speedup vs baseline: 1.3070x; 1.3070x over previous
//
#include <hip/hip_runtime.h>
#include <hip/hip_bf16.h>

typedef __attribute__((ext_vector_type(8))) short bf16x8;
typedef __attribute__((ext_vector_type(4))) float f32x4;

#define C1 0.180336880111112f   // 0.125 * log2(e) : folds the 1/sqrt(64) scale into exp2

static __device__ __forceinline__ unsigned short f2bf(float f) {
    union { float f; unsigned int i; } u; u.f = f;
    unsigned int r = u.i + 0x7fffu + ((u.i >> 16) & 1u);
    return (unsigned short)(r >> 16);
}
// pack two f32 -> two bf16 in one instr (no builtin on gfx950; RTNE)
static __device__ __forceinline__ unsigned int cvt_pk_bf16(float lo, float hi) {
    unsigned int r;
    asm("v_cvt_pk_bf16_f32 %0, %1, %2" : "=v"(r) : "v"(lo), "v"(hi));
    return r;
}

// ---------------- fused prep: cast x, transpose+cast both weights (one dispatch) ----------------
__global__ __launch_bounds__(256)
void prep_kernel(const float* __restrict__ x, const float* __restrict__ wA, const float* __restrict__ wP,
                 unsigned short* __restrict__ xb, unsigned short* __restrict__ wtA,
                 unsigned short* __restrict__ wtP) {
    const int bid = blockIdx.x, tid = threadIdx.x;
    if (bid < 2048) {
        int i0 = bid * 256 + tid;
        #pragma unroll
        for (int it = 0; it < 4; ++it) {
            int i = i0 + it * 524288;
            float4 v = reinterpret_cast<const float4*>(x)[i];
            ushort4 o;
            o.x = f2bf(v.x); o.y = f2bf(v.y); o.z = f2bf(v.z); o.w = f2bf(v.w);
            reinterpret_cast<ushort4*>(xb)[i] = o;
        }
    } else {
        const float* in; unsigned short* out; int R, C, bx, by;
        if (bid < 5120) { int l = bid - 2048; in = wA; out = wtA; R = 1024; C = 3072; bx = l % 96; by = l / 96; }
        else            { int l = bid - 5120; in = wP; out = wtP; R = 1024; C = 1024; bx = l % 32; by = l / 32; }
        __shared__ float tile[32][33];
        const int c0 = bx * 32, r0 = by * 32;
        const int tx = tid & 31, ty = tid >> 5;   // 32 x 8
        #pragma unroll
        for (int i = 0; i < 32; i += 8)
            tile[ty + i][tx] = in[(size_t)(r0 + ty + i) * C + c0 + tx];
        __syncthreads();
        #pragma unroll
        for (int i = 0; i < 32; i += 8)
            out[(size_t)(c0 + ty + i) * R + r0 + tx] = f2bf(tile[tx][ty + i]);
    }
}

// ---------------- GEMM: 128x128 tile, 4 waves, 32KB LDS (4 blocks/CU), T2 swizzle ----------------
// C[m][n] = sum_k A[m][k]*B[n][k], both bf16 K-contiguous.
// MODE 0: fp32 C [M][N].  MODE 1: scatter bf16 Q,K [bh][T][hd], V transposed [bh][hd][T].
template<int MODE>
__global__ __launch_bounds__(256, 4)
void gemm_bt2(const unsigned short* __restrict__ A,
              const unsigned short* __restrict__ B,
              void* __restrict__ Cout,
              int M, int N, int K) {
    __shared__ unsigned short As[8192];   // 128 rows x 64 k, 128B rows, swizzled content
    __shared__ unsigned short Bs[8192];
    const int tid = threadIdx.x;
    const int wave = tid >> 6, lane = tid & 63;
    const int wr = wave >> 1, wc = wave & 1;        // 2x2 waves, each 64x64 out
    const int lg = lane >> 4, lr = lane & 15;
    const int m0 = blockIdx.y * 128, n0 = blockIdx.x * 128;

    // staging: 256 thr x 16B = 4KB (32 rows) per issue, 4 issues each; inverse-swizzled source
    const int slot = tid * 16;
    const int srow = slot >> 7;                                // 0..31
    const int scol = ((slot & 127) ^ ((srow & 7) << 4)) >> 1;
    const int swz = (lr & 7) << 4;

    f32x4 acc[4][4] = {};

    for (int kt = 0; kt < K; kt += 64) {
        #pragma unroll
        for (int i = 0; i < 4; ++i) {
            __builtin_amdgcn_global_load_lds(
                (const __attribute__((address_space(1))) void*)(A + (size_t)(m0 + i * 32 + srow) * K + kt + scol),
                (__attribute__((address_space(3))) void*)(As + ((i * 4096 + slot) >> 1)), 16, 0, 0);
            __builtin_amdgcn_global_load_lds(
                (const __attribute__((address_space(1))) void*)(B + (size_t)(n0 + i * 32 + srow) * K + kt + scol),
                (__attribute__((address_space(3))) void*)(Bs + ((i * 4096 + slot) >> 1)), 16, 0, 0);
        }
        __syncthreads();
        #pragma unroll
        for (int kk = 0; kk < 2; ++kk) {
            bf16x8 af[4], bfr[4];
            #pragma unroll
            for (int mi = 0; mi < 4; ++mi)
                af[mi] = *reinterpret_cast<const bf16x8*>(
                    (const char*)As + (wr * 64 + mi * 16 + lr) * 128 + ((kk * 64 + lg * 16) ^ swz));
            #pragma unroll
            for (int ni = 0; ni < 4; ++ni)
                bfr[ni] = *reinterpret_cast<const bf16x8*>(
                    (const char*)Bs + (wc * 64 + ni * 16 + lr) * 128 + ((kk * 64 + lg * 16) ^ swz));
            #pragma unroll
            for (int mi = 0; mi < 4; ++mi)
                #pragma unroll
                for (int ni = 0; ni < 4; ++ni)
                    acc[mi][ni] = __builtin_amdgcn_mfma_f32_16x16x32_bf16(af[mi], bfr[ni], acc[mi][ni], 0, 0, 0);
        }
        __syncthreads();
    }

    if (MODE == 0) {
        float* C = (float*)Cout;
        #pragma unroll
        for (int mi = 0; mi < 4; ++mi)
            #pragma unroll
            for (int ni = 0; ni < 4; ++ni)
                #pragma unroll
                for (int r = 0; r < 4; ++r) {
                    int row = m0 + wr * 64 + mi * 16 + lg * 4 + r;
                    int col = n0 + wc * 64 + ni * 16 + lr;
                    C[(size_t)row * N + col] = acc[mi][ni][r];
                }
    } else {
        unsigned short* QKV = (unsigned short*)Cout;
        #pragma unroll
        for (int mi = 0; mi < 4; ++mi) {
            int rowb = m0 + wr * 64 + mi * 16 + lg * 4;   // 4 consecutive t
            int bb = rowb >> 11, t = rowb & 2047;
            #pragma unroll
            for (int ni = 0; ni < 4; ++ni) {
                int col = n0 + wc * 64 + ni * 16 + lr;
                int which = col >> 10;            // 0:q 1:k 2:v
                int hh = (col & 1023) >> 6;
                int d = col & 63;
                int bhh = bb * 16 + hh;
                if (which == 2) {
                    // V transposed: [bh][d][T], 4 consecutive t -> one 8B store
                    ushort4 o;
                    o.x = f2bf(acc[mi][ni][0]); o.y = f2bf(acc[mi][ni][1]);
                    o.z = f2bf(acc[mi][ni][2]); o.w = f2bf(acc[mi][ni][3]);
                    *reinterpret_cast<ushort4*>(QKV + (size_t)2 * 8388608 +
                                                ((size_t)bhh * 64 + d) * 2048 + t) = o;
                } else {
                    #pragma unroll
                    for (int r = 0; r < 4; ++r)
                        QKV[(size_t)which * 8388608 +
                            ((size_t)bhh * 2048 + t + r) * 64 + d] = f2bf(acc[mi][ni][r]);
                }
            }
        }
    }
}

// ---------------- flash attention (swapped-operand S^T formulation) ----------------
// Q,K: [bh][T][hd] bf16.  Vt: [bh][hd][T] bf16.  Y out: [B][T][H][hd] bf16.
// KVBLK=64, double-buffered staging. Inner loop VERBATIM from the validated
// 161.8us baseline. NEW: complementary q-tile pairing -- block (bh,y) runs
// qt=15-y then qt=y, so every block costs exactly 34 tile-iterations.
// Grid (64, 8) = 512 uniform blocks = 2/CU (fits 3/CU LDS cap): whole grid
// resident from t=0, no dispatch tail, no imbalance.
__global__ __launch_bounds__(256)
void attn_fwd(const unsigned short* __restrict__ Qb,
              const unsigned short* __restrict__ Kb,
              const unsigned short* __restrict__ Vtb,
              unsigned short* __restrict__ Yb) {
    const int bh = blockIdx.x;
    const int tid = threadIdx.x;
    const int wave = tid >> 6, lane = tid & 63;
    const int lg = lane >> 4, lr = lane & 15;
    const int b = bh >> 4, h = bh & 15;

    __shared__ unsigned short Ks[2][4096];       // [buf][64 k x 64 d] 128B rows, XOR-swizzled
    __shared__ unsigned short Vs[2][4096];       // [buf][64 d x 64 k] 128B rows, XOR-swizzled
    __shared__ unsigned short Ps[4][32][72];     // per-wave P [q][k], 144B row (16B aligned)

    const unsigned short* Qh = Qb + (size_t)bh * (2048 * 64);
    const unsigned short* Kh = Kb + (size_t)bh * (2048 * 64);
    const unsigned short* Vh = Vtb + (size_t)bh * (64 * 2048);

    // staging geometry (linear LDS dest, inverse-swizzled global source)
    const int slot = tid * 16;                                 // byte slot within one 4KB issue
    const int srow = slot >> 7;                                // 0..31 (issue i adds 32)
    const int scol = ((slot & 127) ^ ((srow & 7) << 4)) >> 1;  // swizzled source elem

    const int swz = (lr & 7) << 4;               // read-side swizzle
    const short one_bf = (short)0x3F80;
    const bf16x8 onesv = {one_bf, one_bf, one_bf, one_bf, one_bf, one_bf, one_bf, one_bf};

#define STAGE(bb, kv)                                                                              \
    {                                                                                              \
        _Pragma("unroll")                                                                          \
        for (int i_ = 0; i_ < 2; ++i_) {                                                           \
            __builtin_amdgcn_global_load_lds(                                                      \
                (const __attribute__((address_space(1))) void*)(Kh + (size_t)((kv) + i_ * 32 + srow) * 64 + scol), \
                (__attribute__((address_space(3))) void*)(Ks[bb] + ((i_ * 4096 + slot) >> 1)), 16, 0, 0); \
            __builtin_amdgcn_global_load_lds(                                                      \
                (const __attribute__((address_space(1))) void*)(Vh + (size_t)(i_ * 32 + srow) * 2048 + (kv) + scol), \
                (__attribute__((address_space(3))) void*)(Vs[bb] + ((i_ * 4096 + slot) >> 1)), 16, 0, 0); \
        }                                                                                          \
    }

    #pragma unroll 1
    for (int half = 0; half < 2; ++half) {
        const int qt = half == 0 ? (15 - (int)blockIdx.y) : (int)blockIdx.y;
        const int q0 = qt * 128;
        const int wq0 = q0 + wave * 32;

        // hoist Q fragments (B-operand; wave owns 32 q-rows; col=lr -> q, k-slice = lg*8)
        bf16x8 qf[2][2];
        #pragma unroll
        for (int mi = 0; mi < 2; ++mi)
            #pragma unroll
            for (int kk = 0; kk < 2; ++kk)
                qf[mi][kk] = *reinterpret_cast<const bf16x8*>(
                    Qh + (size_t)(wq0 + mi * 16 + lr) * 64 + kk * 32 + lg * 8);

        f32x4 oacc[4][2] = {};        // O^T[d-block nd][q-block mi]
        f32x4 sumacc[2] = {};         // row-sums (all 4 regs equal), col=q=lr
        float mst[2] = {-1e30f, -1e30f};

        const int nt = 2 * qt + 2;    // kv tiles: 0 .. q0+64
        int cur = 0;

        STAGE(cur, 0);
        asm volatile("s_waitcnt vmcnt(0)" ::: "memory");
        __syncthreads();

        #pragma unroll 1
        for (int t = 0; t < nt; ++t) {
            const int kv0 = t << 6;
            if (t + 1 < nt) STAGE(cur ^ 1, kv0 + 64);   // prefetch next tile

            if (kv0 < wq0 + 32) {                        // tile not fully masked for this wave
                const unsigned short* Kc = Ks[cur];
                const unsigned short* Vc = Vs[cur];

                // ---- S^T = K Q^T : sacc[mi][ni], lane holds S^T[k=kv0+16ni+4lg+r][q=wq0+16mi+lr]
                f32x4 sacc[2][4] = {};
                __builtin_amdgcn_s_setprio(1);
                #pragma unroll
                for (int kk = 0; kk < 2; ++kk) {
                    bf16x8 kf[4];
                    #pragma unroll
                    for (int ni = 0; ni < 4; ++ni)
                        kf[ni] = *reinterpret_cast<const bf16x8*>(
                            (const char*)Kc + (ni * 16 + lr) * 128 + ((kk * 64 + lg * 16) ^ swz));
                    #pragma unroll
                    for (int mi = 0; mi < 2; ++mi)
                        #pragma unroll
                        for (int ni = 0; ni < 4; ++ni)
                            sacc[mi][ni] = __builtin_amdgcn_mfma_f32_16x16x32_bf16(kf[ni], qf[mi][kk], sacc[mi][ni], 0, 0, 0);
                }
                __builtin_amdgcn_s_setprio(0);

                // ---- causal mask: only the diagonal tile of this wave ----
                if (kv0 + 64 > wq0) {
                    #pragma unroll
                    for (int mi = 0; mi < 2; ++mi)
                        #pragma unroll
                        for (int ni = 0; ni < 4; ++ni)
                            #pragma unroll
                            for (int r = 0; r < 4; ++r) {
                                int k = kv0 + ni * 16 + lg * 4 + r;
                                int q = wq0 + mi * 16 + lr;
                                if (k > q) sacc[mi][ni][r] = -1e30f;
                            }
                }

                // ---- online softmax: 16 k-values in-lane + 2 shfls across lg ----
                #pragma unroll
                for (int mi = 0; mi < 2; ++mi) {
                    float m0v = fmaxf(fmaxf(sacc[mi][0][0], sacc[mi][0][1]), fmaxf(sacc[mi][0][2], sacc[mi][0][3]));
                    float m1v = fmaxf(fmaxf(sacc[mi][1][0], sacc[mi][1][1]), fmaxf(sacc[mi][1][2], sacc[mi][1][3]));
                    float m2v = fmaxf(fmaxf(sacc[mi][2][0], sacc[mi][2][1]), fmaxf(sacc[mi][2][2], sacc[mi][2][3]));
                    float m3v = fmaxf(fmaxf(sacc[mi][3][0], sacc[mi][3][1]), fmaxf(sacc[mi][3][2], sacc[mi][3][3]));
                    float mx = fmaxf(fmaxf(m0v, m1v), fmaxf(m2v, m3v));
                    mx = fmaxf(mx, __shfl_xor(mx, 16));
                    mx = fmaxf(mx, __shfl_xor(mx, 32));

                    // defer-max (T13): skip rescale while growth bounded (P <= 2^11.5)
                    if (!__all(mx <= mst[mi] + 64.0f)) {
                        float mnew = fmaxf(mst[mi], mx);
                        float alpha = __builtin_amdgcn_exp2f((mst[mi] - mnew) * C1);
                        mst[mi] = mnew;
                        sumacc[mi] *= alpha;
                        #pragma unroll
                        for (int nd = 0; nd < 4; ++nd)
                            oacc[nd][mi] *= alpha;
                    }
                    float mc = mst[mi] * C1;
                    #pragma unroll
                    for (int ni = 0; ni < 4; ++ni)
                        #pragma unroll
                        for (int r = 0; r < 4; ++r)
                            sacc[mi][ni][r] = __builtin_amdgcn_exp2f(__builtin_fmaf(sacc[mi][ni][r], C1, -mc));

                    // ---- P^T -> Ps[q][k]: 4 consecutive k per (mi,ni) -> packed 8B writes
                    #pragma unroll
                    for (int ni = 0; ni < 4; ++ni) {
                        uint2 w;
                        w.x = cvt_pk_bf16(sacc[mi][ni][0], sacc[mi][ni][1]);
                        w.y = cvt_pk_bf16(sacc[mi][ni][2], sacc[mi][ni][3]);
                        *reinterpret_cast<uint2*>(&Ps[wave][mi * 16 + lr][ni * 16 + lg * 4]) = w;
                    }
                }

                // ---- O^T += V^T P^T ; rowsum via ones-A MFMA ----
                __builtin_amdgcn_s_setprio(1);
                #pragma unroll
                for (int ks = 0; ks < 2; ++ks) {
                    bf16x8 pf[2], vf[4];
                    #pragma unroll
                    for (int mi = 0; mi < 2; ++mi)
                        pf[mi] = *reinterpret_cast<const bf16x8*>(&Ps[wave][mi * 16 + lr][ks * 32 + lg * 8]);
                    #pragma unroll
                    for (int nd = 0; nd < 4; ++nd)
                        vf[nd] = *reinterpret_cast<const bf16x8*>(
                            (const char*)Vc + (nd * 16 + lr) * 128 + ((ks * 64 + lg * 16) ^ swz));
                    #pragma unroll
                    for (int mi = 0; mi < 2; ++mi) {
                        sumacc[mi] = __builtin_amdgcn_mfma_f32_16x16x32_bf16(onesv, pf[mi], sumacc[mi], 0, 0, 0);
                        #pragma unroll
                        for (int nd = 0; nd < 4; ++nd)
                            oacc[nd][mi] = __builtin_amdgcn_mfma_f32_16x16x32_bf16(vf[nd], pf[mi], oacc[nd][mi], 0, 0, 0);
                    }
                }
                __builtin_amdgcn_s_setprio(0);
            }

            // next-tile loads landed + everyone done reading cur
            asm volatile("s_waitcnt vmcnt(0)" ::: "memory");
            __syncthreads();
            cur ^= 1;
        }

        // ---- epilogue: y = O / l, packed 8B stores; lane holds d=16nd+4lg+r, q=16mi+lr ----
        #pragma unroll
        for (int mi = 0; mi < 2; ++mi) {
            float rinv = __builtin_amdgcn_rcpf(sumacc[mi][0]);
            int tq = wq0 + mi * 16 + lr;
            size_t base = (((size_t)(b * 2048 + tq)) * 16 + h) * 64 + lg * 4;
            #pragma unroll
            for (int nd = 0; nd < 4; ++nd) {
                uint2 w;
                w.x = cvt_pk_bf16(oacc[nd][mi][0] * rinv, oacc[nd][mi][1] * rinv);
                w.y = cvt_pk_bf16(oacc[nd][mi][2] * rinv, oacc[nd][mi][3] * rinv);
                *reinterpret_cast<uint2*>(Yb + base + nd * 16) = w;
            }
        }
    }
#undef STAGE
}

// ---------------- launch ----------------
extern "C" void kernel_launch(void* const* d_in, const int* in_sizes, int n_in,
                              void* d_out, int out_size, void* d_ws, size_t ws_size,
                              hipStream_t stream) {
    const float* x      = (const float*)d_in[0];
    const float* w_attn = (const float*)d_in[1];
    const float* w_proj = (const float*)d_in[2];
    float* out = (float*)d_out;

    unsigned short* xb  = (unsigned short*)d_ws;          // 8192*1024
    unsigned short* wtA = xb  + 8388608;                  // 3072*1024
    unsigned short* wtP = wtA + 3145728;                  // 1024*1024
    unsigned short* qkv = wtP + 1048576;                  // q,k: [64][2048][64]; v: [64][64][2048]
    unsigned short* yb  = qkv + 3 * 8388608;              // 8192*1024

    prep_kernel<<<6144, 256, 0, stream>>>(x, w_attn, w_proj, xb, wtA, wtP);

    // qkv: M=8192, N=3072 -> grid (24, 64) = 1536 blocks, 4 blocks/CU (conflict-free 128^2)
    gemm_bt2<1><<<dim3(3072 / 128, 8192 / 128), 256, 0, stream>>>(xb, wtA, qkv, 8192, 3072, 1024);

    // attn: 512 uniform blocks (complementary q-tile pairs), 2 blocks/CU, all resident
    attn_fwd<<<dim3(64, 8), 256, 0, stream>>>(qkv, qkv + 8388608, qkv + 2 * 8388608, yb);

    // proj: M=8192, N=1024 -> grid (8, 64) = 512 blocks, 4 blocks/CU
    gemm_bt2<0><<<dim3(1024 / 128, 8192 / 128), 256, 0, stream>>>(yb, wtP, out, 8192, 1024, 1024);
}